// Round 18
// baseline (488.961 us; speedup 1.0000x reference)
//
#include <hip/hip_runtime.h>

#define S_LEN 2048
#define DMODEL 1024
#define NHEADS 16
#define MLPDIM 4096

typedef float f32x4 __attribute__((ext_vector_type(4)));
typedef __bf16 bf16x8 __attribute__((ext_vector_type(8)));
typedef __bf16 bf16x4 __attribute__((ext_vector_type(4)));

__device__ __forceinline__ void gload_lds16(const void* gsrc, void* ldst) {
  __builtin_amdgcn_global_load_lds(
      (const __attribute__((address_space(1))) void*)gsrc,
      (__attribute__((address_space(3))) void*)ldst, 16, 0, 0);
}

#define BARR() __builtin_amdgcn_s_barrier()
#define VMC(n) do { asm volatile("s_waitcnt vmcnt(" #n ")" ::: "memory"); __builtin_amdgcn_sched_barrier(0); } while (0)

// ---------------- merged prep: 7 transpose+cast jobs + rmsnorm1 + bias concat.
__global__ __launch_bounds__(256) void prep_k(
    const float* __restrict__ qw, const float* __restrict__ kw,
    const float* __restrict__ vw, const float* __restrict__ ow,
    const float* __restrict__ gw, const float* __restrict__ uw,
    const float* __restrict__ dw, __bf16* __restrict__ wqkv,
    __bf16* __restrict__ wo, __bf16* __restrict__ wg, __bf16* __restrict__ wu,
    __bf16* __restrict__ wd, const float* __restrict__ qb,
    const float* __restrict__ kb, const float* __restrict__ vb,
    float* __restrict__ bqkv, const float* __restrict__ x,
    const float* __restrict__ ascale, __bf16* __restrict__ hbuf) {
  __shared__ __bf16 tile[64][66];
  __shared__ float part[4];
  int bid = blockIdx.x, t = threadIdx.x;
  if (bid >= 8192) {  // bias concat
    int i = (bid - 8192) * 256 + t;
    if (i < 1024) bqkv[i] = qb[i];
    else if (i < 2048) bqkv[i] = kb[i - 1024];
    else if (i < 3072) bqkv[i] = vb[i - 2048];
    return;
  }
  if (bid >= 4096) {  // rmsnorm1: x row -> hbuf bf16
    int row = bid - 4096;
    f32x4 v = ((const f32x4*)(x + (size_t)row * DMODEL))[t];
    float ss = v[0] * v[0] + v[1] * v[1] + v[2] * v[2] + v[3] * v[3];
#pragma unroll
    for (int off = 1; off < 64; off <<= 1) ss += __shfl_xor(ss, off, 64);
    if ((t & 63) == 0) part[t >> 6] = ss;
    __syncthreads();
    float tot = part[0] + part[1] + part[2] + part[3];
    float r = rsqrtf(tot * (1.0f / DMODEL) + 1e-6f);
    f32x4 s4 = ((const f32x4*)ascale)[t];
    bf16x4 o;
#pragma unroll
    for (int e = 0; e < 4; ++e) o[e] = (__bf16)(v[e] * r * s4[e]);
    ((bf16x4*)hbuf)[(size_t)row * (DMODEL / 4) + t] = o;
    return;
  }
  const float* in;
  __bf16* out;
  int K, N, bx, by;
  if (bid < 1024) {
    int job = bid >> 8, tt = bid & 255;
    K = 1024; N = 1024; bx = tt & 15; by = tt >> 4;
    in = (job == 0) ? qw : (job == 1) ? kw : (job == 2) ? vw : ow;
    out = (job == 0) ? wqkv : (job == 1) ? wqkv + 1024 * 1024
        : (job == 2) ? wqkv + 2 * 1024 * 1024 : wo;
  } else if (bid < 3072) {
    int job = (bid - 1024) >> 10, tt = (bid - 1024) & 1023;
    K = 1024; N = 4096; bx = tt & 63; by = tt >> 6;
    in = job ? uw : gw;
    out = job ? wu : wg;
  } else {
    int tt = bid - 3072;
    K = 4096; N = 1024; bx = tt & 15; by = tt >> 4;
    in = dw; out = wd;
  }
  int n0 = bx * 64, k0 = by * 64;
  int rr = (t & 63) >> 4, sl = t & 15, wv = t >> 6;
#pragma unroll
  for (int j = 0; j < 4; ++j) {
    int r = wv * 4 + rr + j * 16;
    f32x4 v = *(const f32x4*)(in + (size_t)(k0 + r) * N + n0 + sl * 4);
#pragma unroll
    for (int e = 0; e < 4; ++e) tile[r][sl * 4 + e] = (__bf16)v[e];
  }
  __syncthreads();
#pragma unroll
  for (int j = 0; j < 2; ++j) {
    int u = t + j * 256;
    int n = u >> 3, kc = u & 7;
    bf16x8 o;
#pragma unroll
    for (int e = 0; e < 8; ++e) o[e] = tile[kc * 8 + e][n];
    *(bf16x8*)(out + (size_t)(n0 + n) * K + k0 + kc * 8) = o;
  }
}

// ---------------- RMSNorm (ffn path): x f32 [rows][1024] -> bf16, * scale
__global__ __launch_bounds__(256) void rmsnorm_k(
    const float* __restrict__ x, const float* __restrict__ scale,
    __bf16* __restrict__ out) {
  int row = blockIdx.x, tid = threadIdx.x;
  f32x4 v = ((const f32x4*)(x + (size_t)row * DMODEL))[tid];
  float ss = v[0] * v[0] + v[1] * v[1] + v[2] * v[2] + v[3] * v[3];
#pragma unroll
  for (int off = 1; off < 64; off <<= 1) ss += __shfl_xor(ss, off, 64);
  __shared__ float part[4];
  if ((tid & 63) == 0) part[tid >> 6] = ss;
  __syncthreads();
  float tot = part[0] + part[1] + part[2] + part[3];
  float r = rsqrtf(tot * (1.0f / DMODEL) + 1e-6f);
  f32x4 s4 = ((const f32x4*)scale)[tid];
  bf16x4 o;
#pragma unroll
  for (int e = 0; e < 4; ++e) o[e] = (__bf16)(v[e] * r * s4[e]);
  ((bf16x4*)out)[(size_t)row * (DMODEL / 4) + tid] = o;
}

// ============ QKV GEMM: 128x128 block, wave 64x64, fused permuted-V epilogue
__global__ __launch_bounds__(256, 3) void gemm_qkv(
    const __bf16* __restrict__ A, const __bf16* __restrict__ Bt,
    const float* __restrict__ bias, __bf16* __restrict__ C,
    __bf16* __restrict__ vt, int M, int N, int K) {
  __shared__ __attribute__((aligned(16))) __bf16 As[128 * 64];
  __shared__ __attribute__((aligned(16))) __bf16 Bs[128 * 64];
  int tid = threadIdx.x, lane = tid & 63, wave = tid >> 6;
  int l15 = lane & 15, g4 = lane >> 4;
  int NB = N >> 7, P = M >> 10;
  int xcd = blockIdx.x & 7, j = blockIdx.x >> 3;
  int grp = j / (2 * NB), jj = j - grp * 2 * NB;
  int bm = (xcd * P + grp * 2 + (jj & 1)) * 128;
  int bn = (jj >> 1) * 128;
  int wr = wave >> 1, wc = wave & 1;
  f32x4 acc[4][4] = {};
  const __bf16* Abase = A + (size_t)bm * K;
  const __bf16* Bbase = Bt + (size_t)bn * K;

  for (int k0 = 0; k0 < K; k0 += 64) {
#pragma unroll
    for (int i = 0; i < 4; ++i) {
      int u = tid + i * 256;
      int r = u >> 3, c = (u & 7) ^ (r & 7);
      gload_lds16(Abase + (size_t)r * K + k0 + c * 8, As + u * 8);
      gload_lds16(Bbase + (size_t)r * K + k0 + c * 8, Bs + u * 8);
    }
    __syncthreads();
#pragma unroll
    for (int ks = 0; ks < 2; ++ks) {
      bf16x8 af[4], bfr[4];
#pragma unroll
      for (int m = 0; m < 4; ++m) {
        int r = wr * 64 + m * 16 + l15;
        af[m] = *(const bf16x8*)(As + r * 64 + (((4 * ks + g4) ^ (r & 7)) << 3));
      }
#pragma unroll
      for (int n = 0; n < 4; ++n) {
        int r = wc * 64 + n * 16 + l15;
        bfr[n] = *(const bf16x8*)(Bs + r * 64 + (((4 * ks + g4) ^ (r & 7)) << 3));
      }
      __builtin_amdgcn_s_setprio(1);
#pragma unroll
      for (int m = 0; m < 4; ++m)
#pragma unroll
        for (int n = 0; n < 4; ++n)
          acc[m][n] = __builtin_amdgcn_mfma_f32_16x16x32_bf16(af[m], bfr[n], acc[m][n], 0, 0, 0);
      __builtin_amdgcn_s_setprio(0);
    }
    __syncthreads();
  }
  int r0 = bm + wr * 64 + g4 * 4;
  int c0 = bn + wc * 64 + l15;
  bool isV = (bn >= 2048);
#pragma unroll
  for (int n = 0; n < 4; ++n) {
    int c = c0 + n * 16;
    float bv = bias[c];
#pragma unroll
    for (int m = 0; m < 4; ++m) {
      int rb = r0 + m * 16;
      if (!isV) {
#pragma unroll
        for (int rg = 0; rg < 4; ++rg)
          C[(size_t)(rb + rg) * N + c] = (__bf16)(acc[m][n][rg] + bv);
      } else {
        bf16x4 vv;
#pragma unroll
        for (int rg = 0; rg < 4; ++rg) vv[rg] = (__bf16)(acc[m][n][rg] + bv);
        int b = rb >> 11, s = rb & 2047;
        int sp = (s & ~31) | (((s >> 2) & 3) << 3) | (((s >> 4) & 1) << 2);
        *(bf16x4*)(vt + (size_t)(b * 1024 + c - 2048) * S_LEN + sp) = vv;
      }
    }
  }
}

// ============ fused gate+up GEMM, T2 XOR-swizzled, single-buffer 32KB ========
// R18: min-waves 4 -> 5 (LDS 5x32KB = 160KB exactly; VGPR 64 fits) — the one
// remaining occupancy-POSITIVE knob. All else R14-identical.
__global__ __launch_bounds__(256, 5) void gemm_gu(
    const __bf16* __restrict__ A, const __bf16* __restrict__ Gt,
    const __bf16* __restrict__ Ut, const float* __restrict__ gb,
    const float* __restrict__ ub, __bf16* __restrict__ Cout,
    int M, int N, int K) {
  __shared__ __attribute__((aligned(16))) __bf16 As[128 * 64];
  __shared__ __attribute__((aligned(16))) __bf16 Gs[64 * 64];
  __shared__ __attribute__((aligned(16))) __bf16 Us[64 * 64];
  int tid = threadIdx.x, lane = tid & 63, wave = tid >> 6;
  int l15 = lane & 15, g4 = lane >> 4;
  int lin = blockIdx.x;
  int xcd = lin & 7, idx = lin >> 3;
  int bxl = idx >> 4, byl = idx & 15;
  int bn = ((xcd & 3) * 16 + bxl) * 64;
  int bm = ((xcd >> 2) * 16 + byl) * 128;
  int wr = wave >> 1, wc = wave & 1;
  f32x4 ag[4][2] = {}, au[4][2] = {};
  const __bf16* Abase = A + (size_t)bm * K;
  const __bf16* Gbase = Gt + (size_t)bn * K;
  const __bf16* Ubase = Ut + (size_t)bn * K;

  for (int k0 = 0; k0 < K; k0 += 64) {
#pragma unroll
    for (int j = 0; j < 4; ++j) {
      int u = tid + j * 256;
      int r = u >> 3, c = (u & 7) ^ (r & 7);
      gload_lds16(Abase + (size_t)r * K + k0 + c * 8, As + u * 8);
    }
#pragma unroll
    for (int j = 0; j < 2; ++j) {
      int u = tid + j * 256;
      int r = u >> 3, c = (u & 7) ^ (r & 7);
      gload_lds16(Gbase + (size_t)r * K + k0 + c * 8, Gs + u * 8);
      gload_lds16(Ubase + (size_t)r * K + k0 + c * 8, Us + u * 8);
    }
    __syncthreads();
#pragma unroll
    for (int ks = 0; ks < 2; ++ks) {
      bf16x8 af[4], gf[2], uf[2];
#pragma unroll
      for (int m = 0; m < 4; ++m) {
        int r = wr * 64 + m * 16 + l15;
        af[m] = *(const bf16x8*)(As + r * 64 + (((4 * ks + g4) ^ (r & 7)) << 3));
      }
#pragma unroll
      for (int n = 0; n < 2; ++n) {
        int r = wc * 32 + n * 16 + l15;
        int off = r * 64 + (((4 * ks + g4) ^ (r & 7)) << 3);
        gf[n] = *(const bf16x8*)(Gs + off);
        uf[n] = *(const bf16x8*)(Us + off);
      }
      __builtin_amdgcn_s_setprio(1);
#pragma unroll
      for (int m = 0; m < 4; ++m)
#pragma unroll
        for (int n = 0; n < 2; ++n) {
          ag[m][n] = __builtin_amdgcn_mfma_f32_16x16x32_bf16(af[m], gf[n], ag[m][n], 0, 0, 0);
          au[m][n] = __builtin_amdgcn_mfma_f32_16x16x32_bf16(af[m], uf[n], au[m][n], 0, 0, 0);
        }
      __builtin_amdgcn_s_setprio(0);
    }
    __syncthreads();
  }
  int r0 = bm + wr * 64 + g4 * 4;
  int c0 = bn + wc * 32 + l15;
#pragma unroll
  for (int n = 0; n < 2; ++n) {
    int c = c0 + n * 16;
    float gbv = gb[c], ubv = ub[c];
#pragma unroll
    for (int m = 0; m < 4; ++m) {
      int rb = r0 + m * 16;
#pragma unroll
      for (int rg = 0; rg < 4; ++rg) {
        float g = ag[m][n][rg] + gbv;
        float u = au[m][n][rg] + ubv;
        float v = g / (1.0f + __expf(-g)) * u;
        Cout[(size_t)(rb + rg) * N + c] = (__bf16)v;
      }
    }
  }
}

// ============ 128x64-tile GEMM: T2 swizzle + counted-vmcnt double-buffer =====
template <int OUT_BF16, int RESID, int SILU>
__global__ __launch_bounds__(256, 3) void gemm_n64(
    const __bf16* __restrict__ A, const __bf16* __restrict__ Bt,
    const float* __restrict__ bias, const float* __restrict__ resid,
    const __bf16* __restrict__ aux, void* __restrict__ Cout,
    int M, int N, int K) {
  __shared__ __attribute__((aligned(16))) __bf16 As[2][128 * 64];
  __shared__ __attribute__((aligned(16))) __bf16 Bs[2][64 * 64];
  int tid = threadIdx.x, lane = tid & 63, wave = tid >> 6;
  int l15 = lane & 15, g4 = lane >> 4;
  int NB = N >> 6;
  int xcd = blockIdx.x & 7, j = blockIdx.x >> 3;
  int grp = j / (2 * NB), jj = j - grp * 2 * NB;
  int bm = (xcd * (M >> 10) + grp * 2 + (jj & 1)) * 128;
  int bn = (jj >> 1) * 64;
  int wr = wave >> 1, wc = wave & 1;
  f32x4 acc[4][2] = {};
  const __bf16* Abase = A + (size_t)bm * K;
  const __bf16* Bbase = Bt + (size_t)bn * K;

  auto stage = [&](int k0, int sb) {
#pragma unroll
    for (int i = 0; i < 4; ++i) {
      int u = tid + i * 256;
      int r = u >> 3, c = (u & 7) ^ (r & 7);
      gload_lds16(Abase + (size_t)r * K + k0 + c * 8, As[sb] + u * 8);
    }
#pragma unroll
    for (int i = 0; i < 2; ++i) {
      int u = tid + i * 256;
      int r = u >> 3, c = (u & 7) ^ (r & 7);
      gload_lds16(Bbase + (size_t)r * K + k0 + c * 8, Bs[sb] + u * 8);
    }
  };

  int NT = K >> 6;
  stage(0, 0);
  for (int t = 0; t < NT; ++t) {
    int sb = t & 1;
    if (t + 1 < NT) { stage((t + 1) << 6, sb ^ 1); VMC(6); }
    else { VMC(0); }
    BARR();
#pragma unroll
    for (int ks = 0; ks < 2; ++ks) {
      bf16x8 af[4], bfr[2];
#pragma unroll
      for (int m = 0; m < 4; ++m) {
        int r = wr * 64 + m * 16 + l15;
        af[m] = *(const bf16x8*)(As[sb] + r * 64 + (((4 * ks + g4) ^ (r & 7)) << 3));
      }
#pragma unroll
      for (int n = 0; n < 2; ++n) {
        int r = wc * 32 + n * 16 + l15;
        bfr[n] = *(const bf16x8*)(Bs[sb] + r * 64 + (((4 * ks + g4) ^ (r & 7)) << 3));
      }
      __builtin_amdgcn_s_setprio(1);
#pragma unroll
      for (int m = 0; m < 4; ++m)
#pragma unroll
        for (int n = 0; n < 2; ++n)
          acc[m][n] = __builtin_amdgcn_mfma_f32_16x16x32_bf16(af[m], bfr[n], acc[m][n], 0, 0, 0);
      __builtin_amdgcn_s_setprio(0);
    }
    BARR();
  }
  int r0 = bm + wr * 64 + g4 * 4;
  int c0 = bn + wc * 32 + l15;
#pragma unroll
  for (int n = 0; n < 2; ++n) {
    int c = c0 + n * 16;
    float bv = bias[c];
#pragma unroll
    for (int m = 0; m < 4; ++m) {
      int rb = r0 + m * 16;
#pragma unroll
      for (int rg = 0; rg < 4; ++rg) {
        int r = rb + rg;
        size_t idx = (size_t)r * N + c;
        float v = acc[m][n][rg] + bv;
        if (SILU) {
          float gg = (float)aux[idx];
          v *= gg / (1.0f + __expf(-gg));
        }
        if (RESID) v += resid[idx];
        if (OUT_BF16) ((__bf16*)Cout)[idx] = (__bf16)v;
        else ((float*)Cout)[idx] = v;
      }
    }
  }
}

// ---------------- causal flash attention (R12-proven)
#define SCL2E 0.180336879f /* 0.125 * log2(e) */
__global__ __launch_bounds__(512, 4) void attn_k(
    const __bf16* __restrict__ qkv, const __bf16* __restrict__ vt,
    __bf16* __restrict__ ao) {
  __shared__ __attribute__((aligned(16))) __bf16 Ks[2][128 * 64];
  __shared__ __attribute__((aligned(16))) __bf16 Vs[2][64 * 128];
  int tid = threadIdx.x, lane = tid & 63, w = tid >> 6;
  int l15 = lane & 15, g4 = lane >> 4;
  int bh = blockIdx.x, b = bh >> 4, h = bh & 15;
  int qt = 15 - blockIdx.y;
  int qb = qt * 128;
  int qw = qb + w * 16;
  const __bf16* qkvb = qkv + (size_t)b * S_LEN * 3072 + h * 64;
  const __bf16* kgb = qkvb + 1024;
  const __bf16* vtb = vt + (size_t)b * 1024 * S_LEN + (size_t)(h * 64) * S_LEN;

  bf16x8 qf[2];
#pragma unroll
  for (int ks = 0; ks < 2; ++ks)
    qf[ks] = *(const bf16x8*)(qkvb + (size_t)(qw + l15) * 3072 + 32 * ks + 8 * g4);

  f32x4 oa[4] = {};
  float mrow = -1e30f, lrow = 0.f;
  int q = qw + l15;
  int nt = qt + 1;

  auto stage = [&](int kvb, int buf) {
#pragma unroll
    for (int i = 0; i < 2; ++i) {
      int u = tid + i * 512;
      int r = u >> 3, c = u & 7;
      gload_lds16(kgb + (size_t)(kvb + r) * 3072 + ((c ^ (r & 7)) << 3),
                  Ks[buf] + w * 512 + i * 4096);
    }
#pragma unroll
    for (int i = 0; i < 2; ++i) {
      int u = tid + i * 512;
      int r = u >> 4, cu = u & 15;
      gload_lds16(vtb + (size_t)r * S_LEN + kvb + ((cu ^ (r & 7)) << 3),
                  Vs[buf] + w * 512 + i * 4096);
    }
  };

  stage(0, 0);
  __syncthreads();
  int buf = 0;
  for (int t = 0; t < nt; ++t) {
    int kvb = t * 128;
    if (t + 1 < nt) stage(kvb + 128, buf ^ 1);

    f32x4 sa[8];
#pragma unroll
    for (int i = 0; i < 8; ++i) sa[i] = f32x4{0.f, 0.f, 0.f, 0.f};
#pragma unroll
    for (int st = 0; st < 2; ++st)
#pragma unroll
      for (int ks = 0; ks < 2; ++ks) {
        bf16x8 kf[4];
#pragma unroll
        for (int n = 0; n < 4; ++n) {
          int rr = st * 64 + n * 16 + l15;
          int bc = (64 * ks + 16 * g4) ^ ((rr & 7) << 4);
          kf[n] = *(const bf16x8*)((const char*)Ks[buf] + rr * 128 + bc);
        }
        __builtin_amdgcn_s_setprio(1);
#pragma unroll
        for (int n = 0; n < 4; ++n)
          sa[st * 4 + n] = __builtin_amdgcn_mfma_f32_16x16x32_bf16(kf[n], qf[ks], sa[st * 4 + n], 0, 0, 0);
        __builtin_amdgcn_s_setprio(0);
      }

    bool lastt = (t == nt - 1);
    float nmx = -1e30f;
#pragma unroll
    for (int i = 0; i < 8; ++i)
#pragma unroll
      for (int rg = 0; rg < 4; ++rg) {
        float s = sa[i][rg] * SCL2E;
        if (lastt) {
          int key = kvb + (i >> 2) * 64 + (i & 3) * 16 + 4 * g4 + rg;
          s = (key <= q) ? s : -1e30f;
        }
        sa[i][rg] = s;
        nmx = fmaxf(nmx, s);
      }
    nmx = fmaxf(nmx, __shfl_xor(nmx, 16));
    nmx = fmaxf(nmx, __shfl_xor(nmx, 32));
    float nm;
    if (!__all(nmx <= mrow)) {
      nm = fmaxf(mrow, nmx);
      float sc = exp2f(mrow - nm);
      mrow = nm;
      lrow *= sc;
#pragma unroll
      for (int rg = 0; rg < 4; ++rg) {
        float scq = __shfl(sc, 4 * g4 + rg);
#pragma unroll
        for (int dn = 0; dn < 4; ++dn) oa[dn][rg] *= scq;
      }
    } else {
      nm = mrow;
    }
    float rs = 0.f;
    bf16x8 pa[2][2];
#pragma unroll
    for (int st = 0; st < 2; ++st)
#pragma unroll
      for (int ks = 0; ks < 2; ++ks)
#pragma unroll
        for (int hf = 0; hf < 2; ++hf)
#pragma unroll
          for (int rg = 0; rg < 4; ++rg) {
            float p = exp2f(sa[st * 4 + 2 * ks + hf][rg] - nm);
            rs += p;
            pa[st][ks][hf * 4 + rg] = (__bf16)p;
          }
    rs += __shfl_xor(rs, 16);
    rs += __shfl_xor(rs, 32);
    lrow += rs;

#pragma unroll
    for (int st = 0; st < 2; ++st)
#pragma unroll
      for (int ks = 0; ks < 2; ++ks) {
        __builtin_amdgcn_s_setprio(1);
#pragma unroll
        for (int dn = 0; dn < 4; ++dn) {
          int rr = dn * 16 + l15;
          int swz = (rr & 7) << 4;
          const char* vrow = (const char*)Vs[buf] + rr * 256;
          bf16x8 vf = *(const bf16x8*)(vrow + ((st * 128 + ks * 64 + g4 * 16) ^ swz));
          oa[dn] = __builtin_amdgcn_mfma_f32_16x16x32_bf16(pa[st][ks], vf, oa[dn], 0, 0, 0);
        }
        __builtin_amdgcn_s_setprio(0);
      }
    __syncthreads();
    buf ^= 1;
  }

  __bf16* aobase = ao + (size_t)b * S_LEN * DMODEL + h * 64;
#pragma unroll
  for (int rg = 0; rg < 4; ++rg) {
    float rl = 1.0f / __shfl(lrow, 4 * g4 + rg);
    int qo = qw + 4 * g4 + rg;
#pragma unroll
    for (int dn = 0; dn < 4; ++dn)
      aobase[(size_t)qo * DMODEL + dn * 16 + l15] = (__bf16)(oa[dn][rg] * rl);
  }
}

// ---------------- host side ----------------
#define OFF_WQKV 0
#define OFF_WO 6291456
#define OFF_WG 8388608
#define OFF_WU 16777216
#define OFF_WD 25165824
#define OFF_BQKV 33554432
#define OFF_H 33570816
#define OFF_QKV 41959424
#define OFF_AO 67125248
#define OFF_T 75513856
#define OFF_VT OFF_T /* VT lives in tbuf's region; dead before gemm_gu writes tbuf */
#define OFF_X2 109068288

extern "C" void kernel_launch(void* const* d_in, const int* in_sizes, int n_in,
                              void* d_out, int out_size, void* d_ws, size_t ws_size,
                              hipStream_t stream) {
  (void)in_sizes; (void)n_in; (void)out_size; (void)ws_size;
  const float* x = (const float*)d_in[0];
  const float* attn_scale = (const float*)d_in[2];
  const float* q_w = (const float*)d_in[3];
  const float* q_b = (const float*)d_in[4];
  const float* k_w = (const float*)d_in[5];
  const float* k_b = (const float*)d_in[6];
  const float* v_w = (const float*)d_in[7];
  const float* v_b = (const float*)d_in[8];
  const float* o_w = (const float*)d_in[9];
  const float* o_b = (const float*)d_in[10];
  const float* ffn_scale = (const float*)d_in[11];
  const float* gate_w = (const float*)d_in[12];
  const float* gate_b = (const float*)d_in[13];
  const float* up_w = (const float*)d_in[14];
  const float* up_b = (const float*)d_in[15];
  const float* down_w = (const float*)d_in[16];
  const float* down_b = (const float*)d_in[17];

  char* ws = (char*)d_ws;
  __bf16* wqkv = (__bf16*)(ws + OFF_WQKV);
  __bf16* wo = (__bf16*)(ws + OFF_WO);
  __bf16* wg = (__bf16*)(ws + OFF_WG);
  __bf16* wu = (__bf16*)(ws + OFF_WU);
  __bf16* wd = (__bf16*)(ws + OFF_WD);
  float* bqkv = (float*)(ws + OFF_BQKV);
  __bf16* hbuf = (__bf16*)(ws + OFF_H);
  __bf16* qkvbuf = (__bf16*)(ws + OFF_QKV);
  __bf16* aobuf = (__bf16*)(ws + OFF_AO);
  __bf16* tbuf = (__bf16*)(ws + OFF_T);
  __bf16* vtbuf = (__bf16*)(ws + OFF_VT);
  float* x2 = (float*)(ws + OFF_X2);

  dim3 blk(256);
  // merged prep: 7 transposes + rmsnorm1 + bias concat
  prep_k<<<dim3(8204), blk, 0, stream>>>(q_w, k_w, v_w, o_w, gate_w, up_w, down_w,
                                         wqkv, wo, wg, wu, wd, q_b, k_b, v_b, bqkv,
                                         x, attn_scale, hbuf);
  // attn path (qkv GEMM writes Q,K to qkvbuf and V transposed to vtbuf)
  gemm_qkv<<<dim3(768), blk, 0, stream>>>(hbuf, wqkv, bqkv, qkvbuf, vtbuf, 4096, 3072, 1024);
  attn_k<<<dim3(32, 16), dim3(512), 0, stream>>>(qkvbuf, vtbuf, aobuf);
  gemm_n64<0, 1, 0><<<dim3(512), blk, 0, stream>>>(aobuf, wo, o_b, x, nullptr, x2, 4096, 1024, 1024);
  // ffn path (fused gate+up)
  rmsnorm_k<<<4096, blk, 0, stream>>>(x2, ffn_scale, hbuf);
  gemm_gu<<<dim3(2048), blk, 0, stream>>>(hbuf, wg, wu, gate_b, up_b, tbuf, 4096, 4096, 1024);
  gemm_n64<0, 1, 0><<<dim3(512), blk, 0, stream>>>(tbuf, wd, down_b, x2, nullptr, (float*)d_out, 4096, 1024, 4096);
}

// Round 19
// 240.716 us; speedup vs baseline: 2.0313x; 2.0313x over previous
//
#include <hip/hip_runtime.h>

#define S_LEN 2048
#define DMODEL 1024
#define NHEADS 16
#define MLPDIM 4096

typedef float f32x4 __attribute__((ext_vector_type(4)));
typedef __bf16 bf16x8 __attribute__((ext_vector_type(8)));
typedef __bf16 bf16x4 __attribute__((ext_vector_type(4)));

__device__ __forceinline__ void gload_lds16(const void* gsrc, void* ldst) {
  __builtin_amdgcn_global_load_lds(
      (const __attribute__((address_space(1))) void*)gsrc,
      (__attribute__((address_space(3))) void*)ldst, 16, 0, 0);
}

#define BARR() __builtin_amdgcn_s_barrier()
#define VMC(n) do { asm volatile("s_waitcnt vmcnt(" #n ")" ::: "memory"); __builtin_amdgcn_sched_barrier(0); } while (0)

// ---------------- merged prep: 7 transpose+cast jobs + rmsnorm1 + bias concat.
__global__ __launch_bounds__(256) void prep_k(
    const float* __restrict__ qw, const float* __restrict__ kw,
    const float* __restrict__ vw, const float* __restrict__ ow,
    const float* __restrict__ gw, const float* __restrict__ uw,
    const float* __restrict__ dw, __bf16* __restrict__ wqkv,
    __bf16* __restrict__ wo, __bf16* __restrict__ wg, __bf16* __restrict__ wu,
    __bf16* __restrict__ wd, const float* __restrict__ qb,
    const float* __restrict__ kb, const float* __restrict__ vb,
    float* __restrict__ bqkv, const float* __restrict__ x,
    const float* __restrict__ ascale, __bf16* __restrict__ hbuf) {
  __shared__ __bf16 tile[64][66];
  __shared__ float part[4];
  int bid = blockIdx.x, t = threadIdx.x;
  if (bid >= 8192) {  // bias concat
    int i = (bid - 8192) * 256 + t;
    if (i < 1024) bqkv[i] = qb[i];
    else if (i < 2048) bqkv[i] = kb[i - 1024];
    else if (i < 3072) bqkv[i] = vb[i - 2048];
    return;
  }
  if (bid >= 4096) {  // rmsnorm1: x row -> hbuf bf16
    int row = bid - 4096;
    f32x4 v = ((const f32x4*)(x + (size_t)row * DMODEL))[t];
    float ss = v[0] * v[0] + v[1] * v[1] + v[2] * v[2] + v[3] * v[3];
#pragma unroll
    for (int off = 1; off < 64; off <<= 1) ss += __shfl_xor(ss, off, 64);
    if ((t & 63) == 0) part[t >> 6] = ss;
    __syncthreads();
    float tot = part[0] + part[1] + part[2] + part[3];
    float r = rsqrtf(tot * (1.0f / DMODEL) + 1e-6f);
    f32x4 s4 = ((const f32x4*)ascale)[t];
    bf16x4 o;
#pragma unroll
    for (int e = 0; e < 4; ++e) o[e] = (__bf16)(v[e] * r * s4[e]);
    ((bf16x4*)hbuf)[(size_t)row * (DMODEL / 4) + t] = o;
    return;
  }
  const float* in;
  __bf16* out;
  int K, N, bx, by;
  if (bid < 1024) {
    int job = bid >> 8, tt = bid & 255;
    K = 1024; N = 1024; bx = tt & 15; by = tt >> 4;
    in = (job == 0) ? qw : (job == 1) ? kw : (job == 2) ? vw : ow;
    out = (job == 0) ? wqkv : (job == 1) ? wqkv + 1024 * 1024
        : (job == 2) ? wqkv + 2 * 1024 * 1024 : wo;
  } else if (bid < 3072) {
    int job = (bid - 1024) >> 10, tt = (bid - 1024) & 1023;
    K = 1024; N = 4096; bx = tt & 63; by = tt >> 6;
    in = job ? uw : gw;
    out = job ? wu : wg;
  } else {
    int tt = bid - 3072;
    K = 4096; N = 1024; bx = tt & 15; by = tt >> 4;
    in = dw; out = wd;
  }
  int n0 = bx * 64, k0 = by * 64;
  int rr = (t & 63) >> 4, sl = t & 15, wv = t >> 6;
#pragma unroll
  for (int j = 0; j < 4; ++j) {
    int r = wv * 4 + rr + j * 16;
    f32x4 v = *(const f32x4*)(in + (size_t)(k0 + r) * N + n0 + sl * 4);
#pragma unroll
    for (int e = 0; e < 4; ++e) tile[r][sl * 4 + e] = (__bf16)v[e];
  }
  __syncthreads();
#pragma unroll
  for (int j = 0; j < 2; ++j) {
    int u = t + j * 256;
    int n = u >> 3, kc = u & 7;
    bf16x8 o;
#pragma unroll
    for (int e = 0; e < 8; ++e) o[e] = tile[kc * 8 + e][n];
    *(bf16x8*)(out + (size_t)(n0 + n) * K + k0 + kc * 8) = o;
  }
}

// ---------------- RMSNorm (ffn path): x f32 [rows][1024] -> bf16, * scale
__global__ __launch_bounds__(256) void rmsnorm_k(
    const float* __restrict__ x, const float* __restrict__ scale,
    __bf16* __restrict__ out) {
  int row = blockIdx.x, tid = threadIdx.x;
  f32x4 v = ((const f32x4*)(x + (size_t)row * DMODEL))[tid];
  float ss = v[0] * v[0] + v[1] * v[1] + v[2] * v[2] + v[3] * v[3];
#pragma unroll
  for (int off = 1; off < 64; off <<= 1) ss += __shfl_xor(ss, off, 64);
  __shared__ float part[4];
  if ((tid & 63) == 0) part[tid >> 6] = ss;
  __syncthreads();
  float tot = part[0] + part[1] + part[2] + part[3];
  float r = rsqrtf(tot * (1.0f / DMODEL) + 1e-6f);
  f32x4 s4 = ((const f32x4*)scale)[tid];
  bf16x4 o;
#pragma unroll
  for (int e = 0; e < 4; ++e) o[e] = (__bf16)(v[e] * r * s4[e]);
  ((bf16x4*)out)[(size_t)row * (DMODEL / 4) + tid] = o;
}

// ============ QKV GEMM: 128x128 block, wave 64x64, fused permuted-V epilogue
__global__ __launch_bounds__(256, 3) void gemm_qkv(
    const __bf16* __restrict__ A, const __bf16* __restrict__ Bt,
    const float* __restrict__ bias, __bf16* __restrict__ C,
    __bf16* __restrict__ vt, int M, int N, int K) {
  __shared__ __attribute__((aligned(16))) __bf16 As[128 * 64];
  __shared__ __attribute__((aligned(16))) __bf16 Bs[128 * 64];
  int tid = threadIdx.x, lane = tid & 63, wave = tid >> 6;
  int l15 = lane & 15, g4 = lane >> 4;
  int NB = N >> 7, P = M >> 10;
  int xcd = blockIdx.x & 7, j = blockIdx.x >> 3;
  int grp = j / (2 * NB), jj = j - grp * 2 * NB;
  int bm = (xcd * P + grp * 2 + (jj & 1)) * 128;
  int bn = (jj >> 1) * 128;
  int wr = wave >> 1, wc = wave & 1;
  f32x4 acc[4][4] = {};
  const __bf16* Abase = A + (size_t)bm * K;
  const __bf16* Bbase = Bt + (size_t)bn * K;

  for (int k0 = 0; k0 < K; k0 += 64) {
#pragma unroll
    for (int i = 0; i < 4; ++i) {
      int u = tid + i * 256;
      int r = u >> 3, c = (u & 7) ^ (r & 7);
      gload_lds16(Abase + (size_t)r * K + k0 + c * 8, As + u * 8);
      gload_lds16(Bbase + (size_t)r * K + k0 + c * 8, Bs + u * 8);
    }
    __syncthreads();
#pragma unroll
    for (int ks = 0; ks < 2; ++ks) {
      bf16x8 af[4], bfr[4];
#pragma unroll
      for (int m = 0; m < 4; ++m) {
        int r = wr * 64 + m * 16 + l15;
        af[m] = *(const bf16x8*)(As + r * 64 + (((4 * ks + g4) ^ (r & 7)) << 3));
      }
#pragma unroll
      for (int n = 0; n < 4; ++n) {
        int r = wc * 64 + n * 16 + l15;
        bfr[n] = *(const bf16x8*)(Bs + r * 64 + (((4 * ks + g4) ^ (r & 7)) << 3));
      }
      __builtin_amdgcn_s_setprio(1);
#pragma unroll
      for (int m = 0; m < 4; ++m)
#pragma unroll
        for (int n = 0; n < 4; ++n)
          acc[m][n] = __builtin_amdgcn_mfma_f32_16x16x32_bf16(af[m], bfr[n], acc[m][n], 0, 0, 0);
      __builtin_amdgcn_s_setprio(0);
    }
    __syncthreads();
  }
  int r0 = bm + wr * 64 + g4 * 4;
  int c0 = bn + wc * 64 + l15;
  bool isV = (bn >= 2048);
#pragma unroll
  for (int n = 0; n < 4; ++n) {
    int c = c0 + n * 16;
    float bv = bias[c];
#pragma unroll
    for (int m = 0; m < 4; ++m) {
      int rb = r0 + m * 16;
      if (!isV) {
#pragma unroll
        for (int rg = 0; rg < 4; ++rg)
          C[(size_t)(rb + rg) * N + c] = (__bf16)(acc[m][n][rg] + bv);
      } else {
        bf16x4 vv;
#pragma unroll
        for (int rg = 0; rg < 4; ++rg) vv[rg] = (__bf16)(acc[m][n][rg] + bv);
        int b = rb >> 11, s = rb & 2047;
        int sp = (s & ~31) | (((s >> 2) & 3) << 3) | (((s >> 4) & 1) << 2);
        *(bf16x4*)(vt + (size_t)(b * 1024 + c - 2048) * S_LEN + sp) = vv;
      }
    }
  }
}

// ============ fused gate+up GEMM, T2 XOR-swizzled, single-buffer 32KB ========
// R14-proven plateau: 4 blocks/CU. (R18: min-waves=5 forced VGPR 48 -> acc
// spill -> 342µs. 4 is the max occupancy this kernel's VGPR need permits.)
__global__ __launch_bounds__(256, 4) void gemm_gu(
    const __bf16* __restrict__ A, const __bf16* __restrict__ Gt,
    const __bf16* __restrict__ Ut, const float* __restrict__ gb,
    const float* __restrict__ ub, __bf16* __restrict__ Cout,
    int M, int N, int K) {
  __shared__ __attribute__((aligned(16))) __bf16 As[128 * 64];
  __shared__ __attribute__((aligned(16))) __bf16 Gs[64 * 64];
  __shared__ __attribute__((aligned(16))) __bf16 Us[64 * 64];
  int tid = threadIdx.x, lane = tid & 63, wave = tid >> 6;
  int l15 = lane & 15, g4 = lane >> 4;
  int lin = blockIdx.x;
  int xcd = lin & 7, idx = lin >> 3;
  int bxl = idx >> 4, byl = idx & 15;
  int bn = ((xcd & 3) * 16 + bxl) * 64;
  int bm = ((xcd >> 2) * 16 + byl) * 128;
  int wr = wave >> 1, wc = wave & 1;
  f32x4 ag[4][2] = {}, au[4][2] = {};
  const __bf16* Abase = A + (size_t)bm * K;
  const __bf16* Gbase = Gt + (size_t)bn * K;
  const __bf16* Ubase = Ut + (size_t)bn * K;

  for (int k0 = 0; k0 < K; k0 += 64) {
#pragma unroll
    for (int j = 0; j < 4; ++j) {
      int u = tid + j * 256;
      int r = u >> 3, c = (u & 7) ^ (r & 7);
      gload_lds16(Abase + (size_t)r * K + k0 + c * 8, As + u * 8);
    }
#pragma unroll
    for (int j = 0; j < 2; ++j) {
      int u = tid + j * 256;
      int r = u >> 3, c = (u & 7) ^ (r & 7);
      gload_lds16(Gbase + (size_t)r * K + k0 + c * 8, Gs + u * 8);
      gload_lds16(Ubase + (size_t)r * K + k0 + c * 8, Us + u * 8);
    }
    __syncthreads();
#pragma unroll
    for (int ks = 0; ks < 2; ++ks) {
      bf16x8 af[4], gf[2], uf[2];
#pragma unroll
      for (int m = 0; m < 4; ++m) {
        int r = wr * 64 + m * 16 + l15;
        af[m] = *(const bf16x8*)(As + r * 64 + (((4 * ks + g4) ^ (r & 7)) << 3));
      }
#pragma unroll
      for (int n = 0; n < 2; ++n) {
        int r = wc * 32 + n * 16 + l15;
        int off = r * 64 + (((4 * ks + g4) ^ (r & 7)) << 3);
        gf[n] = *(const bf16x8*)(Gs + off);
        uf[n] = *(const bf16x8*)(Us + off);
      }
      __builtin_amdgcn_s_setprio(1);
#pragma unroll
      for (int m = 0; m < 4; ++m)
#pragma unroll
        for (int n = 0; n < 2; ++n) {
          ag[m][n] = __builtin_amdgcn_mfma_f32_16x16x32_bf16(af[m], gf[n], ag[m][n], 0, 0, 0);
          au[m][n] = __builtin_amdgcn_mfma_f32_16x16x32_bf16(af[m], uf[n], au[m][n], 0, 0, 0);
        }
      __builtin_amdgcn_s_setprio(0);
    }
    __syncthreads();
  }
  int r0 = bm + wr * 64 + g4 * 4;
  int c0 = bn + wc * 32 + l15;
#pragma unroll
  for (int n = 0; n < 2; ++n) {
    int c = c0 + n * 16;
    float gbv = gb[c], ubv = ub[c];
#pragma unroll
    for (int m = 0; m < 4; ++m) {
      int rb = r0 + m * 16;
#pragma unroll
      for (int rg = 0; rg < 4; ++rg) {
        float g = ag[m][n][rg] + gbv;
        float u = au[m][n][rg] + ubv;
        float v = g / (1.0f + __expf(-g)) * u;
        Cout[(size_t)(rb + rg) * N + c] = (__bf16)v;
      }
    }
  }
}

// ============ 128x64-tile GEMM: T2 swizzle + counted-vmcnt double-buffer =====
template <int OUT_BF16, int RESID, int SILU>
__global__ __launch_bounds__(256, 3) void gemm_n64(
    const __bf16* __restrict__ A, const __bf16* __restrict__ Bt,
    const float* __restrict__ bias, const float* __restrict__ resid,
    const __bf16* __restrict__ aux, void* __restrict__ Cout,
    int M, int N, int K) {
  __shared__ __attribute__((aligned(16))) __bf16 As[2][128 * 64];
  __shared__ __attribute__((aligned(16))) __bf16 Bs[2][64 * 64];
  int tid = threadIdx.x, lane = tid & 63, wave = tid >> 6;
  int l15 = lane & 15, g4 = lane >> 4;
  int NB = N >> 6;
  int xcd = blockIdx.x & 7, j = blockIdx.x >> 3;
  int grp = j / (2 * NB), jj = j - grp * 2 * NB;
  int bm = (xcd * (M >> 10) + grp * 2 + (jj & 1)) * 128;
  int bn = (jj >> 1) * 64;
  int wr = wave >> 1, wc = wave & 1;
  f32x4 acc[4][2] = {};
  const __bf16* Abase = A + (size_t)bm * K;
  const __bf16* Bbase = Bt + (size_t)bn * K;

  auto stage = [&](int k0, int sb) {
#pragma unroll
    for (int i = 0; i < 4; ++i) {
      int u = tid + i * 256;
      int r = u >> 3, c = (u & 7) ^ (r & 7);
      gload_lds16(Abase + (size_t)r * K + k0 + c * 8, As[sb] + u * 8);
    }
#pragma unroll
    for (int i = 0; i < 2; ++i) {
      int u = tid + i * 256;
      int r = u >> 3, c = (u & 7) ^ (r & 7);
      gload_lds16(Bbase + (size_t)r * K + k0 + c * 8, Bs[sb] + u * 8);
    }
  };

  int NT = K >> 6;
  stage(0, 0);
  for (int t = 0; t < NT; ++t) {
    int sb = t & 1;
    if (t + 1 < NT) { stage((t + 1) << 6, sb ^ 1); VMC(6); }
    else { VMC(0); }
    BARR();
#pragma unroll
    for (int ks = 0; ks < 2; ++ks) {
      bf16x8 af[4], bfr[2];
#pragma unroll
      for (int m = 0; m < 4; ++m) {
        int r = wr * 64 + m * 16 + l15;
        af[m] = *(const bf16x8*)(As[sb] + r * 64 + (((4 * ks + g4) ^ (r & 7)) << 3));
      }
#pragma unroll
      for (int n = 0; n < 2; ++n) {
        int r = wc * 32 + n * 16 + l15;
        bfr[n] = *(const bf16x8*)(Bs[sb] + r * 64 + (((4 * ks + g4) ^ (r & 7)) << 3));
      }
      __builtin_amdgcn_s_setprio(1);
#pragma unroll
      for (int m = 0; m < 4; ++m)
#pragma unroll
        for (int n = 0; n < 2; ++n)
          acc[m][n] = __builtin_amdgcn_mfma_f32_16x16x32_bf16(af[m], bfr[n], acc[m][n], 0, 0, 0);
      __builtin_amdgcn_s_setprio(0);
    }
    BARR();
  }
  int r0 = bm + wr * 64 + g4 * 4;
  int c0 = bn + wc * 32 + l15;
#pragma unroll
  for (int n = 0; n < 2; ++n) {
    int c = c0 + n * 16;
    float bv = bias[c];
#pragma unroll
    for (int m = 0; m < 4; ++m) {
      int rb = r0 + m * 16;
#pragma unroll
      for (int rg = 0; rg < 4; ++rg) {
        int r = rb + rg;
        size_t idx = (size_t)r * N + c;
        float v = acc[m][n][rg] + bv;
        if (SILU) {
          float gg = (float)aux[idx];
          v *= gg / (1.0f + __expf(-gg));
        }
        if (RESID) v += resid[idx];
        if (OUT_BF16) ((__bf16*)Cout)[idx] = (__bf16)v;
        else ((float*)Cout)[idx] = v;
      }
    }
  }
}

// ---------------- causal flash attention (R12-proven)
#define SCL2E 0.180336879f /* 0.125 * log2(e) */
__global__ __launch_bounds__(512, 4) void attn_k(
    const __bf16* __restrict__ qkv, const __bf16* __restrict__ vt,
    __bf16* __restrict__ ao) {
  __shared__ __attribute__((aligned(16))) __bf16 Ks[2][128 * 64];
  __shared__ __attribute__((aligned(16))) __bf16 Vs[2][64 * 128];
  int tid = threadIdx.x, lane = tid & 63, w = tid >> 6;
  int l15 = lane & 15, g4 = lane >> 4;
  int bh = blockIdx.x, b = bh >> 4, h = bh & 15;
  int qt = 15 - blockIdx.y;
  int qb = qt * 128;
  int qw = qb + w * 16;
  const __bf16* qkvb = qkv + (size_t)b * S_LEN * 3072 + h * 64;
  const __bf16* kgb = qkvb + 1024;
  const __bf16* vtb = vt + (size_t)b * 1024 * S_LEN + (size_t)(h * 64) * S_LEN;

  bf16x8 qf[2];
#pragma unroll
  for (int ks = 0; ks < 2; ++ks)
    qf[ks] = *(const bf16x8*)(qkvb + (size_t)(qw + l15) * 3072 + 32 * ks + 8 * g4);

  f32x4 oa[4] = {};
  float mrow = -1e30f, lrow = 0.f;
  int q = qw + l15;
  int nt = qt + 1;

  auto stage = [&](int kvb, int buf) {
#pragma unroll
    for (int i = 0; i < 2; ++i) {
      int u = tid + i * 512;
      int r = u >> 3, c = u & 7;
      gload_lds16(kgb + (size_t)(kvb + r) * 3072 + ((c ^ (r & 7)) << 3),
                  Ks[buf] + w * 512 + i * 4096);
    }
#pragma unroll
    for (int i = 0; i < 2; ++i) {
      int u = tid + i * 512;
      int r = u >> 4, cu = u & 15;
      gload_lds16(vtb + (size_t)r * S_LEN + kvb + ((cu ^ (r & 7)) << 3),
                  Vs[buf] + w * 512 + i * 4096);
    }
  };

  stage(0, 0);
  __syncthreads();
  int buf = 0;
  for (int t = 0; t < nt; ++t) {
    int kvb = t * 128;
    if (t + 1 < nt) stage(kvb + 128, buf ^ 1);

    f32x4 sa[8];
#pragma unroll
    for (int i = 0; i < 8; ++i) sa[i] = f32x4{0.f, 0.f, 0.f, 0.f};
#pragma unroll
    for (int st = 0; st < 2; ++st)
#pragma unroll
      for (int ks = 0; ks < 2; ++ks) {
        bf16x8 kf[4];
#pragma unroll
        for (int n = 0; n < 4; ++n) {
          int rr = st * 64 + n * 16 + l15;
          int bc = (64 * ks + 16 * g4) ^ ((rr & 7) << 4);
          kf[n] = *(const bf16x8*)((const char*)Ks[buf] + rr * 128 + bc);
        }
        __builtin_amdgcn_s_setprio(1);
#pragma unroll
        for (int n = 0; n < 4; ++n)
          sa[st * 4 + n] = __builtin_amdgcn_mfma_f32_16x16x32_bf16(kf[n], qf[ks], sa[st * 4 + n], 0, 0, 0);
        __builtin_amdgcn_s_setprio(0);
      }

    bool lastt = (t == nt - 1);
    float nmx = -1e30f;
#pragma unroll
    for (int i = 0; i < 8; ++i)
#pragma unroll
      for (int rg = 0; rg < 4; ++rg) {
        float s = sa[i][rg] * SCL2E;
        if (lastt) {
          int key = kvb + (i >> 2) * 64 + (i & 3) * 16 + 4 * g4 + rg;
          s = (key <= q) ? s : -1e30f;
        }
        sa[i][rg] = s;
        nmx = fmaxf(nmx, s);
      }
    nmx = fmaxf(nmx, __shfl_xor(nmx, 16));
    nmx = fmaxf(nmx, __shfl_xor(nmx, 32));
    float nm;
    if (!__all(nmx <= mrow)) {
      nm = fmaxf(mrow, nmx);
      float sc = exp2f(mrow - nm);
      mrow = nm;
      lrow *= sc;
#pragma unroll
      for (int rg = 0; rg < 4; ++rg) {
        float scq = __shfl(sc, 4 * g4 + rg);
#pragma unroll
        for (int dn = 0; dn < 4; ++dn) oa[dn][rg] *= scq;
      }
    } else {
      nm = mrow;
    }
    float rs = 0.f;
    bf16x8 pa[2][2];
#pragma unroll
    for (int st = 0; st < 2; ++st)
#pragma unroll
      for (int ks = 0; ks < 2; ++ks)
#pragma unroll
        for (int hf = 0; hf < 2; ++hf)
#pragma unroll
          for (int rg = 0; rg < 4; ++rg) {
            float p = exp2f(sa[st * 4 + 2 * ks + hf][rg] - nm);
            rs += p;
            pa[st][ks][hf * 4 + rg] = (__bf16)p;
          }
    rs += __shfl_xor(rs, 16);
    rs += __shfl_xor(rs, 32);
    lrow += rs;

#pragma unroll
    for (int st = 0; st < 2; ++st)
#pragma unroll
      for (int ks = 0; ks < 2; ++ks) {
        __builtin_amdgcn_s_setprio(1);
#pragma unroll
        for (int dn = 0; dn < 4; ++dn) {
          int rr = dn * 16 + l15;
          int swz = (rr & 7) << 4;
          const char* vrow = (const char*)Vs[buf] + rr * 256;
          bf16x8 vf = *(const bf16x8*)(vrow + ((st * 128 + ks * 64 + g4 * 16) ^ swz));
          oa[dn] = __builtin_amdgcn_mfma_f32_16x16x32_bf16(pa[st][ks], vf, oa[dn], 0, 0, 0);
        }
        __builtin_amdgcn_s_setprio(0);
      }
    __syncthreads();
    buf ^= 1;
  }

  __bf16* aobase = ao + (size_t)b * S_LEN * DMODEL + h * 64;
#pragma unroll
  for (int rg = 0; rg < 4; ++rg) {
    float rl = 1.0f / __shfl(lrow, 4 * g4 + rg);
    int qo = qw + 4 * g4 + rg;
#pragma unroll
    for (int dn = 0; dn < 4; ++dn)
      aobase[(size_t)qo * DMODEL + dn * 16 + l15] = (__bf16)(oa[dn][rg] * rl);
  }
}

// ---------------- host side ----------------
#define OFF_WQKV 0
#define OFF_WO 6291456
#define OFF_WG 8388608
#define OFF_WU 16777216
#define OFF_WD 25165824
#define OFF_BQKV 33554432
#define OFF_H 33570816
#define OFF_QKV 41959424
#define OFF_AO 67125248
#define OFF_T 75513856
#define OFF_VT OFF_T /* VT lives in tbuf's region; dead before gemm_gu writes tbuf */
#define OFF_X2 109068288

extern "C" void kernel_launch(void* const* d_in, const int* in_sizes, int n_in,
                              void* d_out, int out_size, void* d_ws, size_t ws_size,
                              hipStream_t stream) {
  (void)in_sizes; (void)n_in; (void)out_size; (void)ws_size;
  const float* x = (const float*)d_in[0];
  const float* attn_scale = (const float*)d_in[2];
  const float* q_w = (const float*)d_in[3];
  const float* q_b = (const float*)d_in[4];
  const float* k_w = (const float*)d_in[5];
  const float* k_b = (const float*)d_in[6];
  const float* v_w = (const float*)d_in[7];
  const float* v_b = (const float*)d_in[8];
  const float* o_w = (const float*)d_in[9];
  const float* o_b = (const float*)d_in[10];
  const float* ffn_scale = (const float*)d_in[11];
  const float* gate_w = (const float*)d_in[12];
  const float* gate_b = (const float*)d_in[13];
  const float* up_w = (const float*)d_in[14];
  const float* up_b = (const float*)d_in[15];
  const float* down_w = (const float*)d_in[16];
  const float* down_b = (const float*)d_in[17];

  char* ws = (char*)d_ws;
  __bf16* wqkv = (__bf16*)(ws + OFF_WQKV);
  __bf16* wo = (__bf16*)(ws + OFF_WO);
  __bf16* wg = (__bf16*)(ws + OFF_WG);
  __bf16* wu = (__bf16*)(ws + OFF_WU);
  __bf16* wd = (__bf16*)(ws + OFF_WD);
  float* bqkv = (float*)(ws + OFF_BQKV);
  __bf16* hbuf = (__bf16*)(ws + OFF_H);
  __bf16* qkvbuf = (__bf16*)(ws + OFF_QKV);
  __bf16* aobuf = (__bf16*)(ws + OFF_AO);
  __bf16* tbuf = (__bf16*)(ws + OFF_T);
  __bf16* vtbuf = (__bf16*)(ws + OFF_VT);
  float* x2 = (float*)(ws + OFF_X2);

  dim3 blk(256);
  // merged prep: 7 transposes + rmsnorm1 + bias concat
  prep_k<<<dim3(8204), blk, 0, stream>>>(q_w, k_w, v_w, o_w, gate_w, up_w, down_w,
                                         wqkv, wo, wg, wu, wd, q_b, k_b, v_b, bqkv,
                                         x, attn_scale, hbuf);
  // attn path (qkv GEMM writes Q,K to qkvbuf and V transposed to vtbuf)
  gemm_qkv<<<dim3(768), blk, 0, stream>>>(hbuf, wqkv, bqkv, qkvbuf, vtbuf, 4096, 3072, 1024);
  attn_k<<<dim3(32, 16), dim3(512), 0, stream>>>(qkvbuf, vtbuf, aobuf);
  gemm_n64<0, 1, 0><<<dim3(512), blk, 0, stream>>>(aobuf, wo, o_b, x, nullptr, x2, 4096, 1024, 1024);
  // ffn path (fused gate+up)
  rmsnorm_k<<<4096, blk, 0, stream>>>(x2, ffn_scale, hbuf);
  gemm_gu<<<dim3(2048), blk, 0, stream>>>(hbuf, wg, wu, gate_b, up_b, tbuf, 4096, 4096, 1024);
  gemm_n64<0, 1, 0><<<dim3(512), blk, 0, stream>>>(tbuf, wd, down_b, x2, nullptr, (float*)d_out, 4096, 1024, 4096);
}